// Round 16
// baseline (234.403 us; speedup 1.0000x reference)
//
#include <hip/hip_runtime.h>
#include <hip/hip_bf16.h>

#define BB 4
#define CMv 256
#define CTv 64
#define CAv 128
#define NTOK 6400
#define KVSPLIT 5
#define KVRANGE 1280   /* NTOK/KVSPLIT */
#define NTILES 20      /* KVRANGE/64 */
/* 128^-0.5 * log2(e): softmax runs in exp2 domain */
#define QSCL 0.12753102198064644f

typedef unsigned short u16;
typedef __attribute__((ext_vector_type(8))) short sh8;     // 8 bf16
typedef __attribute__((ext_vector_type(4))) float f32x4;
typedef __attribute__((ext_vector_type(16))) float f32x16;
typedef __attribute__((ext_vector_type(4))) unsigned uint4v;
typedef __attribute__((ext_vector_type(2))) unsigned uint2v;

__device__ __forceinline__ u16 f2bf(float f) {
  return __builtin_bit_cast(u16, __float2bfloat16(f));
}
__device__ __forceinline__ float bf2f(u16 x) {
  unsigned u = ((unsigned)x) << 16;
  return __builtin_bit_cast(float, u);
}
// packed bf16 pair via HW convert (RNE): dst[15:0]=bf16(a), dst[31:16]=bf16(b)
__device__ __forceinline__ unsigned pk2(float a, float b) {
  unsigned r;
  asm("v_cvt_pk_bf16_f32 %0, %1, %2" : "=v"(r) : "v"(a), "v"(b));
  return r;
}
__device__ __forceinline__ f32x16 zero16() {
  f32x16 z;
#pragma unroll
  for (int i = 0; i < 16; i++) z[i] = 0.f;
  return z;
}
typedef const __attribute__((address_space(1))) unsigned int* gas_p;
typedef __attribute__((address_space(3))) unsigned int* las_p;
__device__ __forceinline__ void gl_lds16(const u16* g, u16* l) {
  __builtin_amdgcn_global_load_lds((gas_p)g, (las_p)l, 16, 0, 0);
}

// ---------------- weight prep: fp32 -> bf16, row-major (A-frag ready) ----------------
__global__ __launch_bounds__(256) void prep(const float* __restrict__ wq,
                                            const float* __restrict__ bq,
                                            const float* __restrict__ wk,
                                            const float* __restrict__ wv,
                                            const float* __restrict__ wo,
                                            u16* __restrict__ wqB,
                                            float* __restrict__ bqs,
                                            u16* __restrict__ wkB,
                                            u16* __restrict__ wvB,
                                            u16* __restrict__ woB) {
  const int i0 = blockIdx.x * 256 + threadIdx.x;
  const int stride = gridDim.x * 256;
  for (int i = i0; i < 128 * 256; i += stride) wqB[i] = f2bf(wq[i] * QSCL);
  for (int i = i0; i < 128 * 64; i += stride) { wkB[i] = f2bf(wk[i]); wvB[i] = f2bf(wv[i]); }
  for (int i = i0; i < 256 * 128; i += stride) woB[i] = f2bf(wo[i]);
  for (int i = i0; i < 128; i += stride) bqs[i] = bq[i] * QSCL;
}

// ---------------- MFMA Q + K/V projections (unchanged from R12/R14) ----------------
__global__ __launch_bounds__(512, 2) void qkvproj(const float* __restrict__ met,
                                                  const float* __restrict__ ter,
                                                  const u16* __restrict__ wqB,
                                                  const float* __restrict__ bqs,
                                                  const u16* __restrict__ wkB,
                                                  const float* __restrict__ bk,
                                                  const u16* __restrict__ wvB,
                                                  const float* __restrict__ bv,
                                                  u16* __restrict__ Qtm,
                                                  u16* __restrict__ Ktm,
                                                  u16* __restrict__ Vcm) {
  const int tid = threadIdx.x;
  const int w = tid >> 6;
  const int lane = tid & 63;
  const int l31 = lane & 31;
  const int h = lane >> 5;

  if (blockIdx.x < 200) {
    const int b = blockIdx.x / 50;
    const int tokb = (blockIdx.x % 50) * 128;
    const int chg = (w & 3) * 32;
    const int half = w >> 2;
    const u16* wb = wqB + (size_t)(chg + l31) * 256 + h * 8;
    sh8 af[16];
#pragma unroll
    for (int kk = 0; kk < 16; kk++) af[kk] = *(const sh8*)(wb + kk * 16);
    float bias[16];
#pragma unroll
    for (int r = 0; r < 16; r++) bias[r] = bqs[chg + (r & 3) + 8 * (r >> 2) + 4 * h];
    const float* mp = met + (size_t)b * CMv * NTOK;
#pragma unroll
    for (int ct = 0; ct < 2; ct++) {
      const int tok = tokb + (half * 2 + ct) * 32 + l31;
      f32x16 acc = zero16();
#pragma unroll
      for (int kk = 0; kk < 16; kk++) {
        const float* cp = mp + (size_t)(kk * 16 + 8 * h) * NTOK + tok;
        float x0 = cp[0], x1 = cp[(size_t)NTOK], x2 = cp[(size_t)2 * NTOK],
              x3 = cp[(size_t)3 * NTOK], x4 = cp[(size_t)4 * NTOK],
              x5 = cp[(size_t)5 * NTOK], x6 = cp[(size_t)6 * NTOK],
              x7 = cp[(size_t)7 * NTOK];
        uint4v u = {pk2(x0, x1), pk2(x2, x3), pk2(x4, x5), pk2(x6, x7)};
        acc = __builtin_amdgcn_mfma_f32_32x32x16_bf16(
            af[kk], __builtin_bit_cast(sh8, u), acc, 0, 0, 0);
      }
      u16* qp = Qtm + ((size_t)b * NTOK + tok) * CAv;
#pragma unroll
      for (int rq = 0; rq < 4; rq++) {
        const int ch0 = chg + 8 * rq + 4 * h;
        uint2v d = {pk2(acc[4 * rq + 0] + bias[4 * rq + 0],
                        acc[4 * rq + 1] + bias[4 * rq + 1]),
                    pk2(acc[4 * rq + 2] + bias[4 * rq + 2],
                        acc[4 * rq + 3] + bias[4 * rq + 3])};
        *(uint2v*)(qp + ch0) = d;
      }
    }
  } else {
    const int bx = blockIdx.x - 200;
    const int b = bx / 50;
    const int tokb = (bx % 50) * 128;
    const bool isV = w >= 4;
    const int chg = (w & 3) * 32;
    const u16* wb = (isV ? wvB : wkB) + (size_t)(chg + l31) * 64 + h * 8;
    sh8 af[4];
#pragma unroll
    for (int kk = 0; kk < 4; kk++) af[kk] = *(const sh8*)(wb + kk * 16);
    const float* barr = isV ? bv : bk;
    float bias[16];
#pragma unroll
    for (int r = 0; r < 16; r++) bias[r] = barr[chg + (r & 3) + 8 * (r >> 2) + 4 * h];
    const float* tp = ter + (size_t)b * CTv * NTOK;
#pragma unroll
    for (int ct = 0; ct < 4; ct++) {
      const int tok = tokb + ct * 32 + l31;
      f32x16 acc = zero16();
#pragma unroll
      for (int kk = 0; kk < 4; kk++) {
        const float* cp = tp + (size_t)(kk * 16 + 8 * h) * NTOK + tok;
        float x0 = cp[0], x1 = cp[(size_t)NTOK], x2 = cp[(size_t)2 * NTOK],
              x3 = cp[(size_t)3 * NTOK], x4 = cp[(size_t)4 * NTOK],
              x5 = cp[(size_t)5 * NTOK], x6 = cp[(size_t)6 * NTOK],
              x7 = cp[(size_t)7 * NTOK];
        uint4v u = {pk2(x0, x1), pk2(x2, x3), pk2(x4, x5), pk2(x6, x7)};
        acc = __builtin_amdgcn_mfma_f32_32x32x16_bf16(
            af[kk], __builtin_bit_cast(sh8, u), acc, 0, 0, 0);
      }
      if (!isV) {
        u16* kp = Ktm + ((size_t)b * NTOK + tok) * CAv;
#pragma unroll
        for (int rq = 0; rq < 4; rq++) {
          const int ch0 = chg + 8 * rq + 4 * h;
          uint2v d = {pk2(acc[4 * rq + 0] + bias[4 * rq + 0],
                          acc[4 * rq + 1] + bias[4 * rq + 1]),
                      pk2(acc[4 * rq + 2] + bias[4 * rq + 2],
                          acc[4 * rq + 3] + bias[4 * rq + 3])};
          *(uint2v*)(kp + ch0) = d;
        }
      } else {
#pragma unroll
        for (int r = 0; r < 16; r++) {
          const int ch = chg + (r & 3) + 8 * (r >> 2) + 4 * h;
          Vcm[((size_t)b * CAv + ch) * NTOK + tok] = f2bf(acc[r] + bias[r]);
        }
      }
    }
  }
}

// ---------------- flash attention: D-split waves, register-designed <=128 ----------------
// R15 lesson: demand ~176 at cap 128 spilled. This design FITS the cap:
// 8 waves = 4 q-subtiles x 2 D-halves (dh). Each wave: o[2] (32 AGPR, own 64
// output channels), QK BOTH kv-halves sequentially through ONE s accumulator
// (16 AGPR), softmax consumes s pairwise (4 exp temps). Peak ~120 regs ->
// (512,4) -> 4 waves/SIMD -> 16 waves/CU -> 2 resident blocks. QK duplicated
// per pair (+50% MFMA issue, still << convoy latency). Q_T=128 -> grid 1000
// (=8x125, exact XCD remap). Loop/swizzles/softmax identical to R14.
__global__ __launch_bounds__(512, 4) void attn(const u16* __restrict__ Qtm,
                                               const u16* __restrict__ Ktm,
                                               const u16* __restrict__ Vcm,
                                               u16* __restrict__ Opart,
                                               float* __restrict__ Lpart) {
  __shared__ __align__(16) unsigned char smem[65536];  // 2 x (K 16KB | V 16KB)

  const int tid = threadIdx.x;
  const int w = tid >> 6;
  const int lane = tid & 63;
  const int l31 = lane & 31;
  const int h = lane >> 5;
  const int q = w & 3;         // q-subtile 0..3
  const int dh = w >> 2;       // D-half 0..1

  // XCD-contiguous remap: 1000 = 8 * 125 exactly
  const int x = blockIdx.x & 7;
  const int W = x * 125 + (blockIdx.x >> 3);
  const int g = W / 50;        // segment 0..19 (b*5 + kvq)
  const int qt = W % 50;
  const int b = g / KVSPLIT;
  const int kvq = g % KVSPLIT;
  const int qb0 = qt * 128;
  const int kv00 = kvq * KVRANGE;

  const u16* Qb = Qtm + ((size_t)b * NTOK + qb0 + q * 32 + l31) * CAv;
  const u16* Kb = Ktm + (size_t)b * NTOK * CAv;
  const u16* Vb = Vcm + (size_t)b * CAv * NTOK;

  sh8 qf[8];
#pragma unroll
  for (int kk = 0; kk < 8; kk++) qf[kk] = *(const sh8*)(Qb + kk * 16 + h * 8);

  // K DMA (2 inst/wave, 8 rows x 256B): row groups kr0, kr1 = kr0+4, EACH with
  // its own XOR key (row&15); +64-row advance preserves keys. (R10 fix.)
  const int kr0 = w * 8 + (lane >> 4);
  const int kr1 = kr0 + 4;
  const u16* ksrc0 = Kb + ((size_t)kv00 + kr0) * CAv + (((lane & 15) ^ (kr0 & 15)) * 8);
  const u16* ksrc1 = Kb + ((size_t)kv00 + kr1) * CAv + (((lane & 15) ^ (kr1 & 15)) * 8);
  // V DMA (2 inst/wave, 16 rows x 128B): (c+8)&7 == c&7 so one key works.
  const int vc = w * 16 + (lane >> 3);
  const u16* vsrc = Vb + (size_t)vc * NTOK + kv00 +
                    (((lane & 7) ^ ((lane >> 3) & 7)) * 8);

  // K-frag read offsets: row l31 (kv-half1 at +8192B, same key)
  int koff[8];
#pragma unroll
  for (int kk = 0; kk < 8; kk++)
    koff[kk] = l31 * 256 + (((2 * kk + h) ^ (l31 & 15)) << 4);
  // V-frag read offsets per 16-kv step b2 (V tile rows = channels, 128B rows;
  // wave reads channel rows dh*64 + ct*32 + l31; (c&7)==l31&7)
  int voff[4];
#pragma unroll
  for (int b2 = 0; b2 < 4; b2++)
    voff[b2] = l31 * 128 + (((2 * b2 + h) ^ (l31 & 7)) << 4);

#define STAGE(p)                                               \
  do {                                                         \
    u16* kb_ = (u16*)(smem + (p) * 32768) + w * 1024;          \
    gl_lds16(ksrc0, kb_);                                      \
    gl_lds16(ksrc1, kb_ + 512);                                \
    u16* vb_ = (u16*)(smem + (p) * 32768 + 16384) + w * 1024;  \
    gl_lds16(vsrc, vb_);                                       \
    gl_lds16(vsrc + (size_t)8 * NTOK, vb_ + 512);              \
    ksrc0 += 64 * CAv;                                         \
    ksrc1 += 64 * CAv;                                         \
    vsrc += 64;                                                \
  } while (0)

  STAGE(0);
  asm volatile("s_waitcnt vmcnt(0)" ::: "memory");
  __builtin_amdgcn_s_barrier();

  f32x16 o[2];
  o[0] = zero16();
  o[1] = zero16();
  float lsum = 0.f;

  int buf = 0;
  for (int t = 0; t < NTILES; t++) {
    if (t < NTILES - 1) STAGE(buf ^ 1);
    const unsigned char* kbuf = smem + buf * 32768;
    const unsigned char* vbuf = kbuf + 16384;
    unsigned pkm0[4][2], pkm1[4][2];
    // QK half 0 (kv 0-31) through one s accumulator, consumed immediately
    {
      __builtin_amdgcn_s_setprio(1);
      f32x16 s = zero16();
#pragma unroll
      for (int kk = 0; kk < 8; kk++) {
        sh8 kf = *(const sh8*)(kbuf + koff[kk]);
        s = __builtin_amdgcn_mfma_f32_32x32x16_bf16(kf, qf[kk], s, 0, 0, 0);
      }
      __builtin_amdgcn_s_setprio(0);
#pragma unroll
      for (int rq = 0; rq < 4; rq++) {
        float e0 = __builtin_exp2f(s[4 * rq + 0]);
        float e1 = __builtin_exp2f(s[4 * rq + 1]);
        float e2 = __builtin_exp2f(s[4 * rq + 2]);
        float e3 = __builtin_exp2f(s[4 * rq + 3]);
        lsum += (e0 + e1) + (e2 + e3);
        pkm0[rq][0] = pk2(e0, e1);
        pkm0[rq][1] = pk2(e2, e3);
      }
    }
    // QK half 1 (kv 32-63), same s registers
    {
      __builtin_amdgcn_s_setprio(1);
      f32x16 s = zero16();
#pragma unroll
      for (int kk = 0; kk < 8; kk++) {
        sh8 kf = *(const sh8*)(kbuf + 8192 + koff[kk]);
        s = __builtin_amdgcn_mfma_f32_32x32x16_bf16(kf, qf[kk], s, 0, 0, 0);
      }
      __builtin_amdgcn_s_setprio(0);
#pragma unroll
      for (int rq = 0; rq < 4; rq++) {
        float e0 = __builtin_exp2f(s[4 * rq + 0]);
        float e1 = __builtin_exp2f(s[4 * rq + 1]);
        float e2 = __builtin_exp2f(s[4 * rq + 2]);
        float e3 = __builtin_exp2f(s[4 * rq + 3]);
        lsum += (e0 + e1) + (e2 + e3);
        pkm1[rq][0] = pk2(e0, e1);
        pkm1[rq][1] = pk2(e2, e3);
      }
    }
    // PV: 4 16-kv steps on OWN D-half (channels dh*64 + ct*32, ct=0..1)
#pragma unroll
    for (int xx = 0; xx < 2; xx++) {
#pragma unroll
      for (int b2i = 0; b2i < 2; b2i++) {
        unsigned ow0, ow1, sd0, sd1;
        if (xx == 0) {
          ow0 = h ? pkm0[2 * b2i + 1][0] : pkm0[2 * b2i][0];
          ow1 = h ? pkm0[2 * b2i + 1][1] : pkm0[2 * b2i][1];
          sd0 = h ? pkm0[2 * b2i][0] : pkm0[2 * b2i + 1][0];
          sd1 = h ? pkm0[2 * b2i][1] : pkm0[2 * b2i + 1][1];
        } else {
          ow0 = h ? pkm1[2 * b2i + 1][0] : pkm1[2 * b2i][0];
          ow1 = h ? pkm1[2 * b2i + 1][1] : pkm1[2 * b2i][1];
          sd0 = h ? pkm1[2 * b2i][0] : pkm1[2 * b2i + 1][0];
          sd1 = h ? pkm1[2 * b2i][1] : pkm1[2 * b2i + 1][1];
        }
        unsigned rv0 = (unsigned)__shfl_xor((int)sd0, 32);
        unsigned rv1 = (unsigned)__shfl_xor((int)sd1, 32);
        uint4v fw = {h ? rv0 : ow0, h ? rv1 : ow1, h ? ow0 : rv0, h ? ow1 : rv1};
        sh8 pf = __builtin_bit_cast(sh8, fw);
        const int b2 = xx * 2 + b2i;
        __builtin_amdgcn_s_setprio(1);
#pragma unroll
        for (int ct = 0; ct < 2; ct++) {
          sh8 vf = *(const sh8*)(vbuf + (dh * 2 + ct) * 4096 + voff[b2]);
          o[ct] = __builtin_amdgcn_mfma_f32_32x32x16_bf16(vf, pf, o[ct], 0, 0, 0);
        }
        __builtin_amdgcn_s_setprio(0);
      }
    }
    asm volatile("s_waitcnt vmcnt(0)" ::: "memory");
    __builtin_amdgcn_s_barrier();
    buf ^= 1;
  }
#undef STAGE

  // epilogue: one lsum hop; store unnormalized partial O (own 64 channels) + l
  lsum += __shfl_xor(lsum, 32);
  u16* op = Opart + (((size_t)kvq * BB + b) * NTOK + qb0 + q * 32 + l31) * CAv + dh * 64;
#pragma unroll
  for (int ct = 0; ct < 2; ct++)
#pragma unroll
    for (int rq = 0; rq < 4; rq++) {
      uint2v d = {pk2(o[ct][4 * rq + 0], o[ct][4 * rq + 1]),
                  pk2(o[ct][4 * rq + 2], o[ct][4 * rq + 3])};
      *(uint2v*)(op + ct * 32 + rq * 8 + h * 4) = d;
    }
  if (h == 0 && dh == 0) {
    size_t mi = ((size_t)kvq * BB + b) * NTOK + qb0 + q * 32 + l31;
    Lpart[mi] = lsum;
  }
}

// ---------------- MFMA output projection + merge + residual (unchanged) ----------------
__global__ __launch_bounds__(512, 2) void outproj(const float* __restrict__ met,
                                                  const u16* __restrict__ woB,
                                                  const float* __restrict__ bo,
                                                  const u16* __restrict__ Opart,
                                                  const float* __restrict__ Lpart,
                                                  float* __restrict__ out) {
  const int tid = threadIdx.x;
  const int w = tid >> 6;
  const int lane = tid & 63;
  const int l31 = lane & 31;
  const int h = lane >> 5;

  const int b = blockIdx.x / 100;
  const int tokb = (blockIdx.x % 100) * 64;
  const int chg = (w & 3) * 64;
  const int ct = w >> 2;
  const int tok = tokb + ct * 32 + l31;
  const size_t n = (size_t)b * NTOK + tok;
  const size_t PSTR = (size_t)BB * NTOK;

  const u16* wb0 = woB + (size_t)(chg + l31) * 128 + h * 8;
  const u16* wb1 = woB + (size_t)(chg + 32 + l31) * 128 + h * 8;
  sh8 a0[8], a1[8];
#pragma unroll
  for (int kk = 0; kk < 8; kk++) {
    a0[kk] = *(const sh8*)(wb0 + kk * 16);
    a1[kk] = *(const sh8*)(wb1 + kk * 16);
  }

  float L = 0.f;
#pragma unroll
  for (int i = 0; i < KVSPLIT; i++) L += Lpart[i * PSTR + n];
  const float rL = 1.f / L;

  f32x16 acc0 = zero16(), acc1 = zero16();
#pragma unroll
  for (int kk = 0; kk < 8; kk++) {
    float s[8];
#pragma unroll
    for (int j = 0; j < 8; j++) s[j] = 0.f;
#pragma unroll
    for (int i = 0; i < KVSPLIT; i++) {
      sh8 v = *(const sh8*)(Opart + (i * PSTR + n) * CAv + kk * 16 + 8 * h);
#pragma unroll
      for (int j = 0; j < 8; j++) s[j] += bf2f((u16)v[j]);
    }
    uint4v u = {pk2(s[0] * rL, s[1] * rL), pk2(s[2] * rL, s[3] * rL),
                pk2(s[4] * rL, s[5] * rL), pk2(s[6] * rL, s[7] * rL)};
    sh8 bf = __builtin_bit_cast(sh8, u);
    acc0 = __builtin_amdgcn_mfma_f32_32x32x16_bf16(a0[kk], bf, acc0, 0, 0, 0);
    acc1 = __builtin_amdgcn_mfma_f32_32x32x16_bf16(a1[kk], bf, acc1, 0, 0, 0);
  }
#pragma unroll
  for (int r = 0; r < 16; r++) {
    const int ro = (r & 3) + 8 * (r >> 2) + 4 * h;
    const int ch0 = chg + ro;
    const int ch1 = chg + 32 + ro;
    size_t i0 = ((size_t)b * CMv + ch0) * NTOK + tok;
    size_t i1 = ((size_t)b * CMv + ch1) * NTOK + tok;
    out[i0] = met[i0] + acc0[r] + bo[ch0];
    out[i1] = met[i1] + acc1[r] + bo[ch1];
  }
}

extern "C" void kernel_launch(void* const* d_in, const int* in_sizes, int n_in,
                              void* d_out, int out_size, void* d_ws, size_t ws_size,
                              hipStream_t stream) {
  const float* met = (const float*)d_in[0];
  const float* ter = (const float*)d_in[1];
  const float* wq = (const float*)d_in[2];
  const float* bq = (const float*)d_in[3];
  const float* wk = (const float*)d_in[4];
  const float* bk = (const float*)d_in[5];
  const float* wv = (const float*)d_in[6];
  const float* bv = (const float*)d_in[7];
  const float* wo = (const float*)d_in[8];
  const float* bo = (const float*)d_in[9];
  float* out = (float*)d_out;

  u16* Qtm = (u16*)d_ws;
  u16* Ktm = Qtm + (size_t)BB * NTOK * CAv;
  u16* Vcm = Ktm + (size_t)BB * NTOK * CAv;
  u16* Opart = Vcm + (size_t)BB * NTOK * CAv;
  float* Lpart = (float*)(Opart + (size_t)KVSPLIT * BB * NTOK * CAv);
  u16* wqB = (u16*)(Lpart + (size_t)KVSPLIT * BB * NTOK);
  u16* wkB = wqB + 128 * 256;
  u16* wvB = wkB + 128 * 64;
  u16* woB = wvB + 128 * 64;
  float* bqs = (float*)(woB + 256 * 128);

  prep<<<dim3(40), dim3(256), 0, stream>>>(wq, bq, wk, wv, wo, wqB, bqs, wkB, wvB, woB);
  qkvproj<<<dim3(400), dim3(512), 0, stream>>>(met, ter, wqB, bqs, wkB, bk,
                                               wvB, bv, Qtm, Ktm, Vcm);
  attn<<<dim3(1000), dim3(512), 0, stream>>>(Qtm, Ktm, Vcm, Opart, Lpart);
  outproj<<<dim3(400), dim3(512), 0, stream>>>(met, woB, bo, Opart, Lpart, out);
}

// Round 17
// 218.272 us; speedup vs baseline: 1.0739x; 1.0739x over previous
//
#include <hip/hip_runtime.h>
#include <hip/hip_bf16.h>

#define BB 4
#define CMv 256
#define CTv 64
#define CAv 128
#define NTOK 6400
#define KVSPLIT 5
#define KVRANGE 1280   /* NTOK/KVSPLIT */
#define NTILES 20      /* KVRANGE/64 */
/* 128^-0.5 * log2(e): softmax runs in exp2 domain */
#define QSCL 0.12753102198064644f

typedef unsigned short u16;
typedef __attribute__((ext_vector_type(8))) short sh8;     // 8 bf16
typedef __attribute__((ext_vector_type(4))) float f32x4;
typedef __attribute__((ext_vector_type(16))) float f32x16;
typedef __attribute__((ext_vector_type(4))) unsigned uint4v;
typedef __attribute__((ext_vector_type(2))) unsigned uint2v;

__device__ __forceinline__ u16 f2bf(float f) {
  return __builtin_bit_cast(u16, __float2bfloat16(f));
}
__device__ __forceinline__ float bf2f(u16 x) {
  unsigned u = ((unsigned)x) << 16;
  return __builtin_bit_cast(float, u);
}
// packed bf16 pair via HW convert (RNE): dst[15:0]=bf16(a), dst[31:16]=bf16(b)
__device__ __forceinline__ unsigned pk2(float a, float b) {
  unsigned r;
  asm("v_cvt_pk_bf16_f32 %0, %1, %2" : "=v"(r) : "v"(a), "v"(b));
  return r;
}
__device__ __forceinline__ f32x16 zero16() {
  f32x16 z;
#pragma unroll
  for (int i = 0; i < 16; i++) z[i] = 0.f;
  return z;
}
typedef const __attribute__((address_space(1))) unsigned int* gas_p;
typedef __attribute__((address_space(3))) unsigned int* las_p;
__device__ __forceinline__ void gl_lds16(const u16* g, u16* l) {
  __builtin_amdgcn_global_load_lds((gas_p)g, (las_p)l, 16, 0, 0);
}

// ---------------- weight prep: fp32 -> bf16, row-major (A-frag ready) ----------------
__global__ __launch_bounds__(256) void prep(const float* __restrict__ wq,
                                            const float* __restrict__ bq,
                                            const float* __restrict__ wk,
                                            const float* __restrict__ wv,
                                            const float* __restrict__ wo,
                                            u16* __restrict__ wqB,
                                            float* __restrict__ bqs,
                                            u16* __restrict__ wkB,
                                            u16* __restrict__ wvB,
                                            u16* __restrict__ woB) {
  const int i0 = blockIdx.x * 256 + threadIdx.x;
  const int stride = gridDim.x * 256;
  for (int i = i0; i < 128 * 256; i += stride) wqB[i] = f2bf(wq[i] * QSCL);
  for (int i = i0; i < 128 * 64; i += stride) { wkB[i] = f2bf(wk[i]); wvB[i] = f2bf(wv[i]); }
  for (int i = i0; i < 256 * 128; i += stride) woB[i] = f2bf(wo[i]);
  for (int i = i0; i < 128; i += stride) bqs[i] = bq[i] * QSCL;
}

// ---------------- MFMA Q + K/V projections (unchanged from R12/R14) ----------------
__global__ __launch_bounds__(512, 2) void qkvproj(const float* __restrict__ met,
                                                  const float* __restrict__ ter,
                                                  const u16* __restrict__ wqB,
                                                  const float* __restrict__ bqs,
                                                  const u16* __restrict__ wkB,
                                                  const float* __restrict__ bk,
                                                  const u16* __restrict__ wvB,
                                                  const float* __restrict__ bv,
                                                  u16* __restrict__ Qtm,
                                                  u16* __restrict__ Ktm,
                                                  u16* __restrict__ Vcm) {
  const int tid = threadIdx.x;
  const int w = tid >> 6;
  const int lane = tid & 63;
  const int l31 = lane & 31;
  const int h = lane >> 5;

  if (blockIdx.x < 200) {
    const int b = blockIdx.x / 50;
    const int tokb = (blockIdx.x % 50) * 128;
    const int chg = (w & 3) * 32;
    const int half = w >> 2;
    const u16* wb = wqB + (size_t)(chg + l31) * 256 + h * 8;
    sh8 af[16];
#pragma unroll
    for (int kk = 0; kk < 16; kk++) af[kk] = *(const sh8*)(wb + kk * 16);
    float bias[16];
#pragma unroll
    for (int r = 0; r < 16; r++) bias[r] = bqs[chg + (r & 3) + 8 * (r >> 2) + 4 * h];
    const float* mp = met + (size_t)b * CMv * NTOK;
#pragma unroll
    for (int ct = 0; ct < 2; ct++) {
      const int tok = tokb + (half * 2 + ct) * 32 + l31;
      f32x16 acc = zero16();
#pragma unroll
      for (int kk = 0; kk < 16; kk++) {
        const float* cp = mp + (size_t)(kk * 16 + 8 * h) * NTOK + tok;
        float x0 = cp[0], x1 = cp[(size_t)NTOK], x2 = cp[(size_t)2 * NTOK],
              x3 = cp[(size_t)3 * NTOK], x4 = cp[(size_t)4 * NTOK],
              x5 = cp[(size_t)5 * NTOK], x6 = cp[(size_t)6 * NTOK],
              x7 = cp[(size_t)7 * NTOK];
        uint4v u = {pk2(x0, x1), pk2(x2, x3), pk2(x4, x5), pk2(x6, x7)};
        acc = __builtin_amdgcn_mfma_f32_32x32x16_bf16(
            af[kk], __builtin_bit_cast(sh8, u), acc, 0, 0, 0);
      }
      u16* qp = Qtm + ((size_t)b * NTOK + tok) * CAv;
#pragma unroll
      for (int rq = 0; rq < 4; rq++) {
        const int ch0 = chg + 8 * rq + 4 * h;
        uint2v d = {pk2(acc[4 * rq + 0] + bias[4 * rq + 0],
                        acc[4 * rq + 1] + bias[4 * rq + 1]),
                    pk2(acc[4 * rq + 2] + bias[4 * rq + 2],
                        acc[4 * rq + 3] + bias[4 * rq + 3])};
        *(uint2v*)(qp + ch0) = d;
      }
    }
  } else {
    const int bx = blockIdx.x - 200;
    const int b = bx / 50;
    const int tokb = (bx % 50) * 128;
    const bool isV = w >= 4;
    const int chg = (w & 3) * 32;
    const u16* wb = (isV ? wvB : wkB) + (size_t)(chg + l31) * 64 + h * 8;
    sh8 af[4];
#pragma unroll
    for (int kk = 0; kk < 4; kk++) af[kk] = *(const sh8*)(wb + kk * 16);
    const float* barr = isV ? bv : bk;
    float bias[16];
#pragma unroll
    for (int r = 0; r < 16; r++) bias[r] = barr[chg + (r & 3) + 8 * (r >> 2) + 4 * h];
    const float* tp = ter + (size_t)b * CTv * NTOK;
#pragma unroll
    for (int ct = 0; ct < 4; ct++) {
      const int tok = tokb + ct * 32 + l31;
      f32x16 acc = zero16();
#pragma unroll
      for (int kk = 0; kk < 4; kk++) {
        const float* cp = tp + (size_t)(kk * 16 + 8 * h) * NTOK + tok;
        float x0 = cp[0], x1 = cp[(size_t)NTOK], x2 = cp[(size_t)2 * NTOK],
              x3 = cp[(size_t)3 * NTOK], x4 = cp[(size_t)4 * NTOK],
              x5 = cp[(size_t)5 * NTOK], x6 = cp[(size_t)6 * NTOK],
              x7 = cp[(size_t)7 * NTOK];
        uint4v u = {pk2(x0, x1), pk2(x2, x3), pk2(x4, x5), pk2(x6, x7)};
        acc = __builtin_amdgcn_mfma_f32_32x32x16_bf16(
            af[kk], __builtin_bit_cast(sh8, u), acc, 0, 0, 0);
      }
      if (!isV) {
        u16* kp = Ktm + ((size_t)b * NTOK + tok) * CAv;
#pragma unroll
        for (int rq = 0; rq < 4; rq++) {
          const int ch0 = chg + 8 * rq + 4 * h;
          uint2v d = {pk2(acc[4 * rq + 0] + bias[4 * rq + 0],
                          acc[4 * rq + 1] + bias[4 * rq + 1]),
                      pk2(acc[4 * rq + 2] + bias[4 * rq + 2],
                          acc[4 * rq + 3] + bias[4 * rq + 3])};
          *(uint2v*)(kp + ch0) = d;
        }
      } else {
#pragma unroll
        for (int r = 0; r < 16; r++) {
          const int ch = chg + (r & 3) + 8 * (r >> 2) + 4 * h;
          Vcm[((size_t)b * CAv + ch) * NTOK + tok] = f2bf(acc[r] + bias[r]);
        }
      }
    }
  }
}

// ---------------- flash attention: D-split + IMMEDIATE-CONSUME halves ----------------
// R16 spill root-cause: pkm0+pkm1 co-live -> ~140 regs > 128 cap. Fix: per
// 32-kv half, do {s=QK(half); pkm=exp2(s); PV(half)} to completion -> only ONE
// pkm live; s(16A) and pkm(8V) phases don't overlap. Peak ~118 regs <= 128 ->
// (512,4) -> 4 waves/SIMD -> TWO 8-wave blocks/CU (LDS 64KB x2 = 128 <= 160).
// 8 waves = 4 q-subtiles x 2 D-halves; o[2] = 32 AGPR (own 64 channels); QK
// duplicated across the D-pair (+50% MFMA issue, ~5% of cycle budget).
// Swizzle keys / fragment maps / static-C softmax / XCD remap: R14-verified.
__global__ __launch_bounds__(512, 4) void attn(const u16* __restrict__ Qtm,
                                               const u16* __restrict__ Ktm,
                                               const u16* __restrict__ Vcm,
                                               u16* __restrict__ Opart,
                                               float* __restrict__ Lpart) {
  __shared__ __align__(16) unsigned char smem[65536];  // 2 x (K 16KB | V 16KB)

  const int tid = threadIdx.x;
  const int w = tid >> 6;
  const int lane = tid & 63;
  const int l31 = lane & 31;
  const int h = lane >> 5;
  const int q = w & 3;         // q-subtile 0..3
  const int dh = w >> 2;       // D-half 0..1

  // XCD-contiguous remap: 1000 = 8 * 125 exactly
  const int x = blockIdx.x & 7;
  const int W = x * 125 + (blockIdx.x >> 3);
  const int g = W / 50;        // segment 0..19 (b*5 + kvq)
  const int qt = W % 50;
  const int b = g / KVSPLIT;
  const int kvq = g % KVSPLIT;
  const int qb0 = qt * 128;
  const int kv00 = kvq * KVRANGE;

  const u16* Qb = Qtm + ((size_t)b * NTOK + qb0 + q * 32 + l31) * CAv;
  const u16* Kb = Ktm + (size_t)b * NTOK * CAv;
  const u16* Vb = Vcm + (size_t)b * CAv * NTOK;

  sh8 qf[8];
#pragma unroll
  for (int kk = 0; kk < 8; kk++) qf[kk] = *(const sh8*)(Qb + kk * 16 + h * 8);

  // K DMA (2 inst/wave, 8 rows x 256B): row groups kr0, kr1 = kr0+4, EACH with
  // its own XOR key (row&15); +64-row advance preserves keys. (R10 fix.)
  const int kr0 = w * 8 + (lane >> 4);
  const int kr1 = kr0 + 4;
  const u16* ksrc0 = Kb + ((size_t)kv00 + kr0) * CAv + (((lane & 15) ^ (kr0 & 15)) * 8);
  const u16* ksrc1 = Kb + ((size_t)kv00 + kr1) * CAv + (((lane & 15) ^ (kr1 & 15)) * 8);
  // V DMA (2 inst/wave, 16 rows x 128B): (c+8)&7 == c&7 so one key works.
  const int vc = w * 16 + (lane >> 3);
  const u16* vsrc = Vb + (size_t)vc * NTOK + kv00 +
                    (((lane & 7) ^ ((lane >> 3) & 7)) * 8);

  // K-frag read offsets: row l31 (kv-half1 at +8192B, same key)
  int koff[8];
#pragma unroll
  for (int kk = 0; kk < 8; kk++)
    koff[kk] = l31 * 256 + (((2 * kk + h) ^ (l31 & 15)) << 4);
  // V-frag read offsets per 16-kv step b2 (rows = channels, 128B; (c&7)==l31&7)
  int voff[4];
#pragma unroll
  for (int b2 = 0; b2 < 4; b2++)
    voff[b2] = l31 * 128 + (((2 * b2 + h) ^ (l31 & 7)) << 4);

#define STAGE(p)                                               \
  do {                                                         \
    u16* kb_ = (u16*)(smem + (p) * 32768) + w * 1024;          \
    gl_lds16(ksrc0, kb_);                                      \
    gl_lds16(ksrc1, kb_ + 512);                                \
    u16* vb_ = (u16*)(smem + (p) * 32768 + 16384) + w * 1024;  \
    gl_lds16(vsrc, vb_);                                       \
    gl_lds16(vsrc + (size_t)8 * NTOK, vb_ + 512);              \
    ksrc0 += 64 * CAv;                                         \
    ksrc1 += 64 * CAv;                                         \
    vsrc += 64;                                                \
  } while (0)

  STAGE(0);
  asm volatile("s_waitcnt vmcnt(0)" ::: "memory");
  __builtin_amdgcn_s_barrier();

  f32x16 o[2];
  o[0] = zero16();
  o[1] = zero16();
  float lsum = 0.f;

  int buf = 0;
  for (int t = 0; t < NTILES; t++) {
    if (t < NTILES - 1) STAGE(buf ^ 1);
    const unsigned char* kbuf = smem + buf * 32768;
    const unsigned char* vbuf = kbuf + 16384;
    // per 32-kv half: QK -> softmax -> PV, fully consumed before next half
#pragma unroll
    for (int half = 0; half < 2; half++) {
      __builtin_amdgcn_s_setprio(1);
      f32x16 s = zero16();
#pragma unroll
      for (int kk = 0; kk < 8; kk++) {
        sh8 kf = *(const sh8*)(kbuf + half * 8192 + koff[kk]);
        s = __builtin_amdgcn_mfma_f32_32x32x16_bf16(kf, qf[kk], s, 0, 0, 0);
      }
      __builtin_amdgcn_s_setprio(0);
      unsigned pkm[4][2];
#pragma unroll
      for (int rq = 0; rq < 4; rq++) {
        float e0 = __builtin_exp2f(s[4 * rq + 0]);
        float e1 = __builtin_exp2f(s[4 * rq + 1]);
        float e2 = __builtin_exp2f(s[4 * rq + 2]);
        float e3 = __builtin_exp2f(s[4 * rq + 3]);
        lsum += (e0 + e1) + (e2 + e3);
        pkm[rq][0] = pk2(e0, e1);
        pkm[rq][1] = pk2(e2, e3);
      }
      // PV for this half: b2 = half*2 + {0,1}; own D-half channels
#pragma unroll
      for (int b2i = 0; b2i < 2; b2i++) {
        unsigned ow0 = h ? pkm[2 * b2i + 1][0] : pkm[2 * b2i][0];
        unsigned ow1 = h ? pkm[2 * b2i + 1][1] : pkm[2 * b2i][1];
        unsigned sd0 = h ? pkm[2 * b2i][0] : pkm[2 * b2i + 1][0];
        unsigned sd1 = h ? pkm[2 * b2i][1] : pkm[2 * b2i + 1][1];
        unsigned rv0 = (unsigned)__shfl_xor((int)sd0, 32);
        unsigned rv1 = (unsigned)__shfl_xor((int)sd1, 32);
        uint4v fw = {h ? rv0 : ow0, h ? rv1 : ow1, h ? ow0 : rv0, h ? ow1 : rv1};
        sh8 pf = __builtin_bit_cast(sh8, fw);
        const int b2 = half * 2 + b2i;
        __builtin_amdgcn_s_setprio(1);
#pragma unroll
        for (int ct = 0; ct < 2; ct++) {
          sh8 vf = *(const sh8*)(vbuf + (dh * 2 + ct) * 4096 + voff[b2]);
          o[ct] = __builtin_amdgcn_mfma_f32_32x32x16_bf16(vf, pf, o[ct], 0, 0, 0);
        }
        __builtin_amdgcn_s_setprio(0);
      }
    }
    asm volatile("s_waitcnt vmcnt(0)" ::: "memory");
    __builtin_amdgcn_s_barrier();
    buf ^= 1;
  }
#undef STAGE

  // epilogue: one lsum hop; store unnormalized partial O (own 64 channels) + l
  lsum += __shfl_xor(lsum, 32);
  u16* op = Opart + (((size_t)kvq * BB + b) * NTOK + qb0 + q * 32 + l31) * CAv + dh * 64;
#pragma unroll
  for (int ct = 0; ct < 2; ct++)
#pragma unroll
    for (int rq = 0; rq < 4; rq++) {
      uint2v d = {pk2(o[ct][4 * rq + 0], o[ct][4 * rq + 1]),
                  pk2(o[ct][4 * rq + 2], o[ct][4 * rq + 3])};
      *(uint2v*)(op + ct * 32 + rq * 8 + h * 4) = d;
    }
  if (h == 0 && dh == 0) {
    size_t mi = ((size_t)kvq * BB + b) * NTOK + qb0 + q * 32 + l31;
    Lpart[mi] = lsum;
  }
}

// ---------------- MFMA output projection + merge + residual (unchanged) ----------------
__global__ __launch_bounds__(512, 2) void outproj(const float* __restrict__ met,
                                                  const u16* __restrict__ woB,
                                                  const float* __restrict__ bo,
                                                  const u16* __restrict__ Opart,
                                                  const float* __restrict__ Lpart,
                                                  float* __restrict__ out) {
  const int tid = threadIdx.x;
  const int w = tid >> 6;
  const int lane = tid & 63;
  const int l31 = lane & 31;
  const int h = lane >> 5;

  const int b = blockIdx.x / 100;
  const int tokb = (blockIdx.x % 100) * 64;
  const int chg = (w & 3) * 64;
  const int ct = w >> 2;
  const int tok = tokb + ct * 32 + l31;
  const size_t n = (size_t)b * NTOK + tok;
  const size_t PSTR = (size_t)BB * NTOK;

  const u16* wb0 = woB + (size_t)(chg + l31) * 128 + h * 8;
  const u16* wb1 = woB + (size_t)(chg + 32 + l31) * 128 + h * 8;
  sh8 a0[8], a1[8];
#pragma unroll
  for (int kk = 0; kk < 8; kk++) {
    a0[kk] = *(const sh8*)(wb0 + kk * 16);
    a1[kk] = *(const sh8*)(wb1 + kk * 16);
  }

  float L = 0.f;
#pragma unroll
  for (int i = 0; i < KVSPLIT; i++) L += Lpart[i * PSTR + n];
  const float rL = 1.f / L;

  f32x16 acc0 = zero16(), acc1 = zero16();
#pragma unroll
  for (int kk = 0; kk < 8; kk++) {
    float s[8];
#pragma unroll
    for (int j = 0; j < 8; j++) s[j] = 0.f;
#pragma unroll
    for (int i = 0; i < KVSPLIT; i++) {
      sh8 v = *(const sh8*)(Opart + (i * PSTR + n) * CAv + kk * 16 + 8 * h);
#pragma unroll
      for (int j = 0; j < 8; j++) s[j] += bf2f((u16)v[j]);
    }
    uint4v u = {pk2(s[0] * rL, s[1] * rL), pk2(s[2] * rL, s[3] * rL),
                pk2(s[4] * rL, s[5] * rL), pk2(s[6] * rL, s[7] * rL)};
    sh8 bf = __builtin_bit_cast(sh8, u);
    acc0 = __builtin_amdgcn_mfma_f32_32x32x16_bf16(a0[kk], bf, acc0, 0, 0, 0);
    acc1 = __builtin_amdgcn_mfma_f32_32x32x16_bf16(a1[kk], bf, acc1, 0, 0, 0);
  }
#pragma unroll
  for (int r = 0; r < 16; r++) {
    const int ro = (r & 3) + 8 * (r >> 2) + 4 * h;
    const int ch0 = chg + ro;
    const int ch1 = chg + 32 + ro;
    size_t i0 = ((size_t)b * CMv + ch0) * NTOK + tok;
    size_t i1 = ((size_t)b * CMv + ch1) * NTOK + tok;
    out[i0] = met[i0] + acc0[r] + bo[ch0];
    out[i1] = met[i1] + acc1[r] + bo[ch1];
  }
}

extern "C" void kernel_launch(void* const* d_in, const int* in_sizes, int n_in,
                              void* d_out, int out_size, void* d_ws, size_t ws_size,
                              hipStream_t stream) {
  const float* met = (const float*)d_in[0];
  const float* ter = (const float*)d_in[1];
  const float* wq = (const float*)d_in[2];
  const float* bq = (const float*)d_in[3];
  const float* wk = (const float*)d_in[4];
  const float* bk = (const float*)d_in[5];
  const float* wv = (const float*)d_in[6];
  const float* bv = (const float*)d_in[7];
  const float* wo = (const float*)d_in[8];
  const float* bo = (const float*)d_in[9];
  float* out = (float*)d_out;

  u16* Qtm = (u16*)d_ws;
  u16* Ktm = Qtm + (size_t)BB * NTOK * CAv;
  u16* Vcm = Ktm + (size_t)BB * NTOK * CAv;
  u16* Opart = Vcm + (size_t)BB * NTOK * CAv;
  float* Lpart = (float*)(Opart + (size_t)KVSPLIT * BB * NTOK * CAv);
  u16* wqB = (u16*)(Lpart + (size_t)KVSPLIT * BB * NTOK);
  u16* wkB = wqB + 128 * 256;
  u16* wvB = wkB + 128 * 64;
  u16* woB = wvB + 128 * 64;
  float* bqs = (float*)(woB + 256 * 128);

  prep<<<dim3(40), dim3(256), 0, stream>>>(wq, bq, wk, wv, wo, wqB, bqs, wkB, wvB, woB);
  qkvproj<<<dim3(400), dim3(512), 0, stream>>>(met, ter, wqB, bqs, wkB, bk,
                                               wvB, bv, Qtm, Ktm, Vcm);
  attn<<<dim3(1000), dim3(512), 0, stream>>>(Qtm, Ktm, Vcm, Opart, Lpart);
  outproj<<<dim3(400), dim3(512), 0, stream>>>(met, woB, bo, Opart, Lpart, out);
}

// Round 18
// 171.117 us; speedup vs baseline: 1.3698x; 1.2756x over previous
//
#include <hip/hip_runtime.h>
#include <hip/hip_bf16.h>

#define BB 4
#define CMv 256
#define CTv 64
#define CAv 128
#define NTOK 6400
#define KVSPLIT 5
#define KVRANGE 1280   /* NTOK/KVSPLIT */
#define NTILES 20      /* KVRANGE/64 */
/* 128^-0.5 * log2(e): softmax runs in exp2 domain */
#define QSCL 0.12753102198064644f

typedef unsigned short u16;
typedef __attribute__((ext_vector_type(8))) short sh8;     // 8 bf16
typedef __attribute__((ext_vector_type(4))) float f32x4;
typedef __attribute__((ext_vector_type(16))) float f32x16;
typedef __attribute__((ext_vector_type(4))) unsigned uint4v;
typedef __attribute__((ext_vector_type(2))) unsigned uint2v;

__device__ __forceinline__ u16 f2bf(float f) {
  return __builtin_bit_cast(u16, __float2bfloat16(f));
}
__device__ __forceinline__ float bf2f(u16 x) {
  unsigned u = ((unsigned)x) << 16;
  return __builtin_bit_cast(float, u);
}
// packed bf16 pair via HW convert (RNE): dst[15:0]=bf16(a), dst[31:16]=bf16(b)
__device__ __forceinline__ unsigned pk2(float a, float b) {
  unsigned r;
  asm("v_cvt_pk_bf16_f32 %0, %1, %2" : "=v"(r) : "v"(a), "v"(b));
  return r;
}
__device__ __forceinline__ f32x16 zero16() {
  f32x16 z;
#pragma unroll
  for (int i = 0; i < 16; i++) z[i] = 0.f;
  return z;
}
typedef const __attribute__((address_space(1))) unsigned int* gas_p;
typedef __attribute__((address_space(3))) unsigned int* las_p;
__device__ __forceinline__ void gl_lds16(const u16* g, u16* l) {
  __builtin_amdgcn_global_load_lds((gas_p)g, (las_p)l, 16, 0, 0);
}

// ---------------- weight prep: fp32 -> bf16, row-major (A-frag ready) ----------------
__global__ __launch_bounds__(256) void prep(const float* __restrict__ wq,
                                            const float* __restrict__ bq,
                                            const float* __restrict__ wk,
                                            const float* __restrict__ wv,
                                            const float* __restrict__ wo,
                                            u16* __restrict__ wqB,
                                            float* __restrict__ bqs,
                                            u16* __restrict__ wkB,
                                            u16* __restrict__ wvB,
                                            u16* __restrict__ woB) {
  const int i0 = blockIdx.x * 256 + threadIdx.x;
  const int stride = gridDim.x * 256;
  for (int i = i0; i < 128 * 256; i += stride) wqB[i] = f2bf(wq[i] * QSCL);
  for (int i = i0; i < 128 * 64; i += stride) { wkB[i] = f2bf(wk[i]); wvB[i] = f2bf(wv[i]); }
  for (int i = i0; i < 256 * 128; i += stride) woB[i] = f2bf(wo[i]);
  for (int i = i0; i < 128; i += stride) bqs[i] = bq[i] * QSCL;
}

// ---------------- MFMA Q + K/V projections (unchanged from R12/R14) ----------------
__global__ __launch_bounds__(512, 2) void qkvproj(const float* __restrict__ met,
                                                  const float* __restrict__ ter,
                                                  const u16* __restrict__ wqB,
                                                  const float* __restrict__ bqs,
                                                  const u16* __restrict__ wkB,
                                                  const float* __restrict__ bk,
                                                  const u16* __restrict__ wvB,
                                                  const float* __restrict__ bv,
                                                  u16* __restrict__ Qtm,
                                                  u16* __restrict__ Ktm,
                                                  u16* __restrict__ Vcm) {
  const int tid = threadIdx.x;
  const int w = tid >> 6;
  const int lane = tid & 63;
  const int l31 = lane & 31;
  const int h = lane >> 5;

  if (blockIdx.x < 200) {
    const int b = blockIdx.x / 50;
    const int tokb = (blockIdx.x % 50) * 128;
    const int chg = (w & 3) * 32;
    const int half = w >> 2;
    const u16* wb = wqB + (size_t)(chg + l31) * 256 + h * 8;
    sh8 af[16];
#pragma unroll
    for (int kk = 0; kk < 16; kk++) af[kk] = *(const sh8*)(wb + kk * 16);
    float bias[16];
#pragma unroll
    for (int r = 0; r < 16; r++) bias[r] = bqs[chg + (r & 3) + 8 * (r >> 2) + 4 * h];
    const float* mp = met + (size_t)b * CMv * NTOK;
#pragma unroll
    for (int ct = 0; ct < 2; ct++) {
      const int tok = tokb + (half * 2 + ct) * 32 + l31;
      f32x16 acc = zero16();
#pragma unroll
      for (int kk = 0; kk < 16; kk++) {
        const float* cp = mp + (size_t)(kk * 16 + 8 * h) * NTOK + tok;
        float x0 = cp[0], x1 = cp[(size_t)NTOK], x2 = cp[(size_t)2 * NTOK],
              x3 = cp[(size_t)3 * NTOK], x4 = cp[(size_t)4 * NTOK],
              x5 = cp[(size_t)5 * NTOK], x6 = cp[(size_t)6 * NTOK],
              x7 = cp[(size_t)7 * NTOK];
        uint4v u = {pk2(x0, x1), pk2(x2, x3), pk2(x4, x5), pk2(x6, x7)};
        acc = __builtin_amdgcn_mfma_f32_32x32x16_bf16(
            af[kk], __builtin_bit_cast(sh8, u), acc, 0, 0, 0);
      }
      u16* qp = Qtm + ((size_t)b * NTOK + tok) * CAv;
#pragma unroll
      for (int rq = 0; rq < 4; rq++) {
        const int ch0 = chg + 8 * rq + 4 * h;
        uint2v d = {pk2(acc[4 * rq + 0] + bias[4 * rq + 0],
                        acc[4 * rq + 1] + bias[4 * rq + 1]),
                    pk2(acc[4 * rq + 2] + bias[4 * rq + 2],
                        acc[4 * rq + 3] + bias[4 * rq + 3])};
        *(uint2v*)(qp + ch0) = d;
      }
    }
  } else {
    const int bx = blockIdx.x - 200;
    const int b = bx / 50;
    const int tokb = (bx % 50) * 128;
    const bool isV = w >= 4;
    const int chg = (w & 3) * 32;
    const u16* wb = (isV ? wvB : wkB) + (size_t)(chg + l31) * 64 + h * 8;
    sh8 af[4];
#pragma unroll
    for (int kk = 0; kk < 4; kk++) af[kk] = *(const sh8*)(wb + kk * 16);
    const float* barr = isV ? bv : bk;
    float bias[16];
#pragma unroll
    for (int r = 0; r < 16; r++) bias[r] = barr[chg + (r & 3) + 8 * (r >> 2) + 4 * h];
    const float* tp = ter + (size_t)b * CTv * NTOK;
#pragma unroll
    for (int ct = 0; ct < 4; ct++) {
      const int tok = tokb + ct * 32 + l31;
      f32x16 acc = zero16();
#pragma unroll
      for (int kk = 0; kk < 4; kk++) {
        const float* cp = tp + (size_t)(kk * 16 + 8 * h) * NTOK + tok;
        float x0 = cp[0], x1 = cp[(size_t)NTOK], x2 = cp[(size_t)2 * NTOK],
              x3 = cp[(size_t)3 * NTOK], x4 = cp[(size_t)4 * NTOK],
              x5 = cp[(size_t)5 * NTOK], x6 = cp[(size_t)6 * NTOK],
              x7 = cp[(size_t)7 * NTOK];
        uint4v u = {pk2(x0, x1), pk2(x2, x3), pk2(x4, x5), pk2(x6, x7)};
        acc = __builtin_amdgcn_mfma_f32_32x32x16_bf16(
            af[kk], __builtin_bit_cast(sh8, u), acc, 0, 0, 0);
      }
      if (!isV) {
        u16* kp = Ktm + ((size_t)b * NTOK + tok) * CAv;
#pragma unroll
        for (int rq = 0; rq < 4; rq++) {
          const int ch0 = chg + 8 * rq + 4 * h;
          uint2v d = {pk2(acc[4 * rq + 0] + bias[4 * rq + 0],
                          acc[4 * rq + 1] + bias[4 * rq + 1]),
                      pk2(acc[4 * rq + 2] + bias[4 * rq + 2],
                          acc[4 * rq + 3] + bias[4 * rq + 3])};
          *(uint2v*)(kp + ch0) = d;
        }
      } else {
#pragma unroll
        for (int r = 0; r < 16; r++) {
          const int ch = chg + (r & 3) + 8 * (r >> 2) + 4 * h;
          Vcm[((size_t)b * CAv + ch) * NTOK + tok] = f2bf(acc[r] + bias[r]);
        }
      }
    }
  }
}

// ---------------- flash attention: R14 body + 2-deep pipeline (T4) ----------------
// R14 (125.5us) limiter: single vmcnt(0) waits on tile t+1's 32KB DMA that had
// only ONE compute phase to land -> ~6.5k exposed cycles/tile. Fix: triple
// buffer (3x32KB=96KB), stage t+2 at top of iter t, counted fence vmcnt(4)
// (= tile t+1's 4 DMAs done; t+2's 4 may fly) -> each tile's DMA gets TWO
// compute+barrier periods. Registers/math/swizzles identical to R14
// (84 VGPR + 64 AGPR, 2 waves/SIMD). Occupancy path abandoned: R15/16/17
// proved higher occupancy doesn't help this kernel.
__global__ __launch_bounds__(512, 2) void attn(const u16* __restrict__ Qtm,
                                               const u16* __restrict__ Ktm,
                                               const u16* __restrict__ Vcm,
                                               u16* __restrict__ Opart,
                                               float* __restrict__ Lpart) {
  __shared__ __align__(16) unsigned char smem[98304];  // 3 x (K 16KB | V 16KB)

  const int tid = threadIdx.x;
  const int w = tid >> 6;
  const int lane = tid & 63;
  const int l31 = lane & 31;
  const int h = lane >> 5;

  // XCD-contiguous remap (500 = 8*62 + 4: XCDs 0-3 get 63 blocks, 4-7 get 62)
  const int x = blockIdx.x & 7;
  const int W = x * 62 + (x < 4 ? x : 4) + (blockIdx.x >> 3);
  const int g = W / 25;        // segment 0..19 (b*5 + kvq)
  const int qt = W % 25;
  const int b = g / KVSPLIT;
  const int kvq = g % KVSPLIT;
  const int qb0 = qt * 256;
  const int kv00 = kvq * KVRANGE;

  const u16* Qb = Qtm + ((size_t)b * NTOK + qb0 + w * 32 + l31) * CAv;
  const u16* Kb = Ktm + (size_t)b * NTOK * CAv;
  const u16* Vb = Vcm + (size_t)b * CAv * NTOK;

  sh8 qf[8];
#pragma unroll
  for (int kk = 0; kk < 8; kk++) qf[kk] = *(const sh8*)(Qb + kk * 16 + h * 8);

  const int kr0 = w * 8 + (lane >> 4);
  const int kr1 = kr0 + 4;
  const u16* ksrc0 = Kb + ((size_t)kv00 + kr0) * CAv + (((lane & 15) ^ (kr0 & 15)) * 8);
  const u16* ksrc1 = Kb + ((size_t)kv00 + kr1) * CAv + (((lane & 15) ^ (kr1 & 15)) * 8);
  const int vc = w * 16 + (lane >> 3);
  const u16* vsrc = Vb + (size_t)vc * NTOK + kv00 +
                    (((lane & 7) ^ ((lane >> 3) & 7)) * 8);

  int koff[8];
#pragma unroll
  for (int kk = 0; kk < 8; kk++)
    koff[kk] = l31 * 256 + (((2 * kk + h) ^ (l31 & 15)) << 4);
  int voff[4];
#pragma unroll
  for (int b2 = 0; b2 < 4; b2++)
    voff[b2] = l31 * 128 + (((2 * b2 + h) ^ (l31 & 7)) << 4);

#define STAGE(p)                                               \
  do {                                                         \
    u16* kb_ = (u16*)(smem + (p) * 32768) + w * 1024;          \
    gl_lds16(ksrc0, kb_);                                      \
    gl_lds16(ksrc1, kb_ + 512);                                \
    u16* vb_ = (u16*)(smem + (p) * 32768 + 16384) + w * 1024;  \
    gl_lds16(vsrc, vb_);                                       \
    gl_lds16(vsrc + (size_t)8 * NTOK, vb_ + 512);              \
    ksrc0 += 64 * CAv;                                         \
    ksrc1 += 64 * CAv;                                         \
    vsrc += 64;                                                \
  } while (0)

  // prologue: stage tiles 0,1; confirm tile 0 (tile 1's 4 DMAs stay in flight)
  STAGE(0);
  STAGE(1);
  asm volatile("s_waitcnt vmcnt(4)" ::: "memory");
  __builtin_amdgcn_s_barrier();

  f32x16 o[4];
#pragma unroll
  for (int i = 0; i < 4; i++) o[i] = zero16();
  float lsum = 0.f;

  int buf = 0, sb = 2;
  for (int t = 0; t < NTILES; t++) {
    if (t < NTILES - 2) STAGE(sb);       // issue tile t+2 (4 DMAs)
    const unsigned char* kbuf = smem + buf * 32768;
    const unsigned char* vbuf = kbuf + 16384;
    __builtin_amdgcn_s_setprio(1);
    f32x16 s0 = zero16(), s1 = zero16();
#pragma unroll
    for (int kk = 0; kk < 8; kk++) {
      sh8 kfa = *(const sh8*)(kbuf + koff[kk]);
      sh8 kfb = *(const sh8*)(kbuf + 8192 + koff[kk]);
      s0 = __builtin_amdgcn_mfma_f32_32x32x16_bf16(kfa, qf[kk], s0, 0, 0, 0);
      s1 = __builtin_amdgcn_mfma_f32_32x32x16_bf16(kfb, qf[kk], s1, 0, 0, 0);
    }
    __builtin_amdgcn_s_setprio(0);
    // static-C softmax: P = exp2(S); pack via v_cvt_pk
    f32x16 p0, p1;
#pragma unroll
    for (int r = 0; r < 16; r++) {
      p0[r] = __builtin_exp2f(s0[r]);
      p1[r] = __builtin_exp2f(s1[r]);
    }
#pragma unroll
    for (int r = 0; r < 16; r++) lsum += p0[r] + p1[r];
    unsigned pkm0[4][2], pkm1[4][2];
#pragma unroll
    for (int rq = 0; rq < 4; rq++) {
      pkm0[rq][0] = pk2(p0[4 * rq + 0], p0[4 * rq + 1]);
      pkm0[rq][1] = pk2(p0[4 * rq + 2], p0[4 * rq + 3]);
      pkm1[rq][0] = pk2(p1[4 * rq + 0], p1[4 * rq + 1]);
      pkm1[rq][1] = pk2(p1[4 * rq + 2], p1[4 * rq + 3]);
    }
#pragma unroll
    for (int xx = 0; xx < 2; xx++) {
#pragma unroll
      for (int b2i = 0; b2i < 2; b2i++) {
        unsigned ow0, ow1, sd0, sd1;
        if (xx == 0) {
          ow0 = h ? pkm0[2 * b2i + 1][0] : pkm0[2 * b2i][0];
          ow1 = h ? pkm0[2 * b2i + 1][1] : pkm0[2 * b2i][1];
          sd0 = h ? pkm0[2 * b2i][0] : pkm0[2 * b2i + 1][0];
          sd1 = h ? pkm0[2 * b2i][1] : pkm0[2 * b2i + 1][1];
        } else {
          ow0 = h ? pkm1[2 * b2i + 1][0] : pkm1[2 * b2i][0];
          ow1 = h ? pkm1[2 * b2i + 1][1] : pkm1[2 * b2i][1];
          sd0 = h ? pkm1[2 * b2i][0] : pkm1[2 * b2i + 1][0];
          sd1 = h ? pkm1[2 * b2i][1] : pkm1[2 * b2i + 1][1];
        }
        unsigned rv0 = (unsigned)__shfl_xor((int)sd0, 32);
        unsigned rv1 = (unsigned)__shfl_xor((int)sd1, 32);
        uint4v fw = {h ? rv0 : ow0, h ? rv1 : ow1, h ? ow0 : rv0, h ? ow1 : rv1};
        sh8 pf = __builtin_bit_cast(sh8, fw);
        const int b2 = xx * 2 + b2i;
        __builtin_amdgcn_s_setprio(1);
#pragma unroll
        for (int ct = 0; ct < 4; ct++) {
          sh8 vf = *(const sh8*)(vbuf + ct * 4096 + voff[b2]);
          o[ct] = __builtin_amdgcn_mfma_f32_32x32x16_bf16(vf, pf, o[ct], 0, 0, 0);
        }
        __builtin_amdgcn_s_setprio(0);
      }
    }
    // counted fence (T4): tile t+1's 4 DMAs must be done; tile t+2's may fly
    if (t < NTILES - 2) {
      asm volatile("s_waitcnt vmcnt(4)" ::: "memory");
    } else {
      asm volatile("s_waitcnt vmcnt(0)" ::: "memory");
    }
    __builtin_amdgcn_s_barrier();
    buf = (buf == 2) ? 0 : buf + 1;
    sb = (sb == 2) ? 0 : sb + 1;
  }
#undef STAGE

  lsum += __shfl_xor(lsum, 32);
  u16* op = Opart + (((size_t)kvq * BB + b) * NTOK + qb0 + w * 32 + l31) * CAv;
#pragma unroll
  for (int ct = 0; ct < 4; ct++)
#pragma unroll
    for (int rq = 0; rq < 4; rq++) {
      uint2v d = {pk2(o[ct][4 * rq + 0], o[ct][4 * rq + 1]),
                  pk2(o[ct][4 * rq + 2], o[ct][4 * rq + 3])};
      *(uint2v*)(op + ct * 32 + rq * 8 + h * 4) = d;
    }
  if (h == 0) {
    size_t mi = ((size_t)kvq * BB + b) * NTOK + qb0 + w * 32 + l31;
    Lpart[mi] = lsum;
  }
}

// ---------------- MFMA output projection + merge + residual (unchanged) ----------------
__global__ __launch_bounds__(512, 2) void outproj(const float* __restrict__ met,
                                                  const u16* __restrict__ woB,
                                                  const float* __restrict__ bo,
                                                  const u16* __restrict__ Opart,
                                                  const float* __restrict__ Lpart,
                                                  float* __restrict__ out) {
  const int tid = threadIdx.x;
  const int w = tid >> 6;
  const int lane = tid & 63;
  const int l31 = lane & 31;
  const int h = lane >> 5;

  const int b = blockIdx.x / 100;
  const int tokb = (blockIdx.x % 100) * 64;
  const int chg = (w & 3) * 64;
  const int ct = w >> 2;
  const int tok = tokb + ct * 32 + l31;
  const size_t n = (size_t)b * NTOK + tok;
  const size_t PSTR = (size_t)BB * NTOK;

  const u16* wb0 = woB + (size_t)(chg + l31) * 128 + h * 8;
  const u16* wb1 = woB + (size_t)(chg + 32 + l31) * 128 + h * 8;
  sh8 a0[8], a1[8];
#pragma unroll
  for (int kk = 0; kk < 8; kk++) {
    a0[kk] = *(const sh8*)(wb0 + kk * 16);
    a1[kk] = *(const sh8*)(wb1 + kk * 16);
  }

  float L = 0.f;
#pragma unroll
  for (int i = 0; i < KVSPLIT; i++) L += Lpart[i * PSTR + n];
  const float rL = 1.f / L;

  f32x16 acc0 = zero16(), acc1 = zero16();
#pragma unroll
  for (int kk = 0; kk < 8; kk++) {
    float s[8];
#pragma unroll
    for (int j = 0; j < 8; j++) s[j] = 0.f;
#pragma unroll
    for (int i = 0; i < KVSPLIT; i++) {
      sh8 v = *(const sh8*)(Opart + (i * PSTR + n) * CAv + kk * 16 + 8 * h);
#pragma unroll
      for (int j = 0; j < 8; j++) s[j] += bf2f((u16)v[j]);
    }
    uint4v u = {pk2(s[0] * rL, s[1] * rL), pk2(s[2] * rL, s[3] * rL),
                pk2(s[4] * rL, s[5] * rL), pk2(s[6] * rL, s[7] * rL)};
    sh8 bf = __builtin_bit_cast(sh8, u);
    acc0 = __builtin_amdgcn_mfma_f32_32x32x16_bf16(a0[kk], bf, acc0, 0, 0, 0);
    acc1 = __builtin_amdgcn_mfma_f32_32x32x16_bf16(a1[kk], bf, acc1, 0, 0, 0);
  }
#pragma unroll
  for (int r = 0; r < 16; r++) {
    const int ro = (r & 3) + 8 * (r >> 2) + 4 * h;
    const int ch0 = chg + ro;
    const int ch1 = chg + 32 + ro;
    size_t i0 = ((size_t)b * CMv + ch0) * NTOK + tok;
    size_t i1 = ((size_t)b * CMv + ch1) * NTOK + tok;
    out[i0] = met[i0] + acc0[r] + bo[ch0];
    out[i1] = met[i1] + acc1[r] + bo[ch1];
  }
}

extern "C" void kernel_launch(void* const* d_in, const int* in_sizes, int n_in,
                              void* d_out, int out_size, void* d_ws, size_t ws_size,
                              hipStream_t stream) {
  const float* met = (const float*)d_in[0];
  const float* ter = (const float*)d_in[1];
  const float* wq = (const float*)d_in[2];
  const float* bq = (const float*)d_in[3];
  const float* wk = (const float*)d_in[4];
  const float* bk = (const float*)d_in[5];
  const float* wv = (const float*)d_in[6];
  const float* bv = (const float*)d_in[7];
  const float* wo = (const float*)d_in[8];
  const float* bo = (const float*)d_in[9];
  float* out = (float*)d_out;

  u16* Qtm = (u16*)d_ws;
  u16* Ktm = Qtm + (size_t)BB * NTOK * CAv;
  u16* Vcm = Ktm + (size_t)BB * NTOK * CAv;
  u16* Opart = Vcm + (size_t)BB * NTOK * CAv;
  float* Lpart = (float*)(Opart + (size_t)KVSPLIT * BB * NTOK * CAv);
  u16* wqB = (u16*)(Lpart + (size_t)KVSPLIT * BB * NTOK);
  u16* wkB = wqB + 128 * 256;
  u16* wvB = wkB + 128 * 64;
  u16* woB = wvB + 128 * 64;
  float* bqs = (float*)(woB + 256 * 128);

  prep<<<dim3(40), dim3(256), 0, stream>>>(wq, bq, wk, wv, wo, wqB, bqs, wkB, wvB, woB);
  qkvproj<<<dim3(400), dim3(512), 0, stream>>>(met, ter, wqB, bqs, wkB, bk,
                                               wvB, bv, Qtm, Ktm, Vcm);
  attn<<<dim3(500), dim3(512), 0, stream>>>(Qtm, Ktm, Vcm, Opart, Lpart);
  outproj<<<dim3(400), dim3(512), 0, stream>>>(met, woB, bo, Opart, Lpart, out);
}

// Round 19
// 170.653 us; speedup vs baseline: 1.3736x; 1.0027x over previous
//
#include <hip/hip_runtime.h>
#include <hip/hip_bf16.h>

#define BB 4
#define CMv 256
#define CTv 64
#define CAv 128
#define NTOK 6400
#define KVSPLIT 5
#define KVRANGE 1280   /* NTOK/KVSPLIT */
#define NTILES 20      /* KVRANGE/64 */
/* 128^-0.5 * log2(e): softmax runs in exp2 domain */
#define QSCL 0.12753102198064644f

typedef unsigned short u16;
typedef __attribute__((ext_vector_type(8))) short sh8;     // 8 bf16
typedef __attribute__((ext_vector_type(4))) float f32x4;
typedef __attribute__((ext_vector_type(16))) float f32x16;
typedef __attribute__((ext_vector_type(4))) unsigned uint4v;
typedef __attribute__((ext_vector_type(2))) unsigned uint2v;

__device__ __forceinline__ u16 f2bf(float f) {
  return __builtin_bit_cast(u16, __float2bfloat16(f));
}
__device__ __forceinline__ float bf2f(u16 x) {
  unsigned u = ((unsigned)x) << 16;
  return __builtin_bit_cast(float, u);
}
// packed bf16 pair via HW convert (RNE): dst[15:0]=bf16(a), dst[31:16]=bf16(b)
__device__ __forceinline__ unsigned pk2(float a, float b) {
  unsigned r;
  asm("v_cvt_pk_bf16_f32 %0, %1, %2" : "=v"(r) : "v"(a), "v"(b));
  return r;
}
__device__ __forceinline__ f32x16 zero16() {
  f32x16 z;
#pragma unroll
  for (int i = 0; i < 16; i++) z[i] = 0.f;
  return z;
}
typedef const __attribute__((address_space(1))) unsigned int* gas_p;
typedef __attribute__((address_space(3))) unsigned int* las_p;
__device__ __forceinline__ void gl_lds16(const u16* g, u16* l) {
  __builtin_amdgcn_global_load_lds((gas_p)g, (las_p)l, 16, 0, 0);
}

// ---------------- weight prep: fp32 -> bf16, row-major (A-frag ready) ----------------
__global__ __launch_bounds__(256) void prep(const float* __restrict__ wq,
                                            const float* __restrict__ bq,
                                            const float* __restrict__ wk,
                                            const float* __restrict__ wv,
                                            const float* __restrict__ wo,
                                            u16* __restrict__ wqB,
                                            float* __restrict__ bqs,
                                            u16* __restrict__ wkB,
                                            u16* __restrict__ wvB,
                                            u16* __restrict__ woB) {
  const int i0 = blockIdx.x * 256 + threadIdx.x;
  const int stride = gridDim.x * 256;
  for (int i = i0; i < 128 * 256; i += stride) wqB[i] = f2bf(wq[i] * QSCL);
  for (int i = i0; i < 128 * 64; i += stride) { wkB[i] = f2bf(wk[i]); wvB[i] = f2bf(wv[i]); }
  for (int i = i0; i < 256 * 128; i += stride) woB[i] = f2bf(wo[i]);
  for (int i = i0; i < 128; i += stride) bqs[i] = bq[i] * QSCL;
}

// ---------------- MFMA Q + K/V projections (unchanged from R12/R14) ----------------
__global__ __launch_bounds__(512, 2) void qkvproj(const float* __restrict__ met,
                                                  const float* __restrict__ ter,
                                                  const u16* __restrict__ wqB,
                                                  const float* __restrict__ bqs,
                                                  const u16* __restrict__ wkB,
                                                  const float* __restrict__ bk,
                                                  const u16* __restrict__ wvB,
                                                  const float* __restrict__ bv,
                                                  u16* __restrict__ Qtm,
                                                  u16* __restrict__ Ktm,
                                                  u16* __restrict__ Vcm) {
  const int tid = threadIdx.x;
  const int w = tid >> 6;
  const int lane = tid & 63;
  const int l31 = lane & 31;
  const int h = lane >> 5;

  if (blockIdx.x < 200) {
    const int b = blockIdx.x / 50;
    const int tokb = (blockIdx.x % 50) * 128;
    const int chg = (w & 3) * 32;
    const int half = w >> 2;
    const u16* wb = wqB + (size_t)(chg + l31) * 256 + h * 8;
    sh8 af[16];
#pragma unroll
    for (int kk = 0; kk < 16; kk++) af[kk] = *(const sh8*)(wb + kk * 16);
    float bias[16];
#pragma unroll
    for (int r = 0; r < 16; r++) bias[r] = bqs[chg + (r & 3) + 8 * (r >> 2) + 4 * h];
    const float* mp = met + (size_t)b * CMv * NTOK;
#pragma unroll
    for (int ct = 0; ct < 2; ct++) {
      const int tok = tokb + (half * 2 + ct) * 32 + l31;
      f32x16 acc = zero16();
#pragma unroll
      for (int kk = 0; kk < 16; kk++) {
        const float* cp = mp + (size_t)(kk * 16 + 8 * h) * NTOK + tok;
        float x0 = cp[0], x1 = cp[(size_t)NTOK], x2 = cp[(size_t)2 * NTOK],
              x3 = cp[(size_t)3 * NTOK], x4 = cp[(size_t)4 * NTOK],
              x5 = cp[(size_t)5 * NTOK], x6 = cp[(size_t)6 * NTOK],
              x7 = cp[(size_t)7 * NTOK];
        uint4v u = {pk2(x0, x1), pk2(x2, x3), pk2(x4, x5), pk2(x6, x7)};
        acc = __builtin_amdgcn_mfma_f32_32x32x16_bf16(
            af[kk], __builtin_bit_cast(sh8, u), acc, 0, 0, 0);
      }
      u16* qp = Qtm + ((size_t)b * NTOK + tok) * CAv;
#pragma unroll
      for (int rq = 0; rq < 4; rq++) {
        const int ch0 = chg + 8 * rq + 4 * h;
        uint2v d = {pk2(acc[4 * rq + 0] + bias[4 * rq + 0],
                        acc[4 * rq + 1] + bias[4 * rq + 1]),
                    pk2(acc[4 * rq + 2] + bias[4 * rq + 2],
                        acc[4 * rq + 3] + bias[4 * rq + 3])};
        *(uint2v*)(qp + ch0) = d;
      }
    }
  } else {
    const int bx = blockIdx.x - 200;
    const int b = bx / 50;
    const int tokb = (bx % 50) * 128;
    const bool isV = w >= 4;
    const int chg = (w & 3) * 32;
    const u16* wb = (isV ? wvB : wkB) + (size_t)(chg + l31) * 64 + h * 8;
    sh8 af[4];
#pragma unroll
    for (int kk = 0; kk < 4; kk++) af[kk] = *(const sh8*)(wb + kk * 16);
    const float* barr = isV ? bv : bk;
    float bias[16];
#pragma unroll
    for (int r = 0; r < 16; r++) bias[r] = barr[chg + (r & 3) + 8 * (r >> 2) + 4 * h];
    const float* tp = ter + (size_t)b * CTv * NTOK;
#pragma unroll
    for (int ct = 0; ct < 4; ct++) {
      const int tok = tokb + ct * 32 + l31;
      f32x16 acc = zero16();
#pragma unroll
      for (int kk = 0; kk < 4; kk++) {
        const float* cp = tp + (size_t)(kk * 16 + 8 * h) * NTOK + tok;
        float x0 = cp[0], x1 = cp[(size_t)NTOK], x2 = cp[(size_t)2 * NTOK],
              x3 = cp[(size_t)3 * NTOK], x4 = cp[(size_t)4 * NTOK],
              x5 = cp[(size_t)5 * NTOK], x6 = cp[(size_t)6 * NTOK],
              x7 = cp[(size_t)7 * NTOK];
        uint4v u = {pk2(x0, x1), pk2(x2, x3), pk2(x4, x5), pk2(x6, x7)};
        acc = __builtin_amdgcn_mfma_f32_32x32x16_bf16(
            af[kk], __builtin_bit_cast(sh8, u), acc, 0, 0, 0);
      }
      if (!isV) {
        u16* kp = Ktm + ((size_t)b * NTOK + tok) * CAv;
#pragma unroll
        for (int rq = 0; rq < 4; rq++) {
          const int ch0 = chg + 8 * rq + 4 * h;
          uint2v d = {pk2(acc[4 * rq + 0] + bias[4 * rq + 0],
                          acc[4 * rq + 1] + bias[4 * rq + 1]),
                      pk2(acc[4 * rq + 2] + bias[4 * rq + 2],
                          acc[4 * rq + 3] + bias[4 * rq + 3])};
          *(uint2v*)(kp + ch0) = d;
        }
      } else {
#pragma unroll
        for (int r = 0; r < 16; r++) {
          const int ch = chg + (r & 3) + 8 * (r >> 2) + 4 * h;
          Vcm[((size_t)b * CAv + ch) * NTOK + tok] = f2bf(acc[r] + bias[r]);
        }
      }
    }
  }
}

// ---------------- flash attention: 4-wave blocks -> 2 desynced blocks/CU ----------------
// R13/R18 (pipeline depth) flat, R15/16/17 (occupancy) worse => the limiter is
// the intra-block barrier CONVOY: all 8 waves of ONE resident block stall
// together at every fence. Fix at CONSTANT register/math cost: 4-wave blocks
// (Q_T=128, LDS 64KB) -> TWO independent blocks co-resident per CU (LDS 128KB,
// same 2 waves/SIMD at 148 regs) whose barriers desynchronize -> block B
// issues while block A drains (m114 overlap). K staging: 4 per-instruction
// XOR-keyed pointers (key (4i+(lane>>4))&15, no wrap; R10 rule). V: one key.
// Math/swizzles/static-C softmax/XCD remap identical to R14.
__global__ __launch_bounds__(256, 2) void attn(const u16* __restrict__ Qtm,
                                               const u16* __restrict__ Ktm,
                                               const u16* __restrict__ Vcm,
                                               u16* __restrict__ Opart,
                                               float* __restrict__ Lpart) {
  __shared__ __align__(16) unsigned char smem[65536];  // 2 x (K 16KB | V 16KB)

  const int tid = threadIdx.x;
  const int w = tid >> 6;        // wave 0..3 = q-subtile
  const int lane = tid & 63;
  const int l31 = lane & 31;
  const int h = lane >> 5;

  // XCD-contiguous remap: 1000 = 8 * 125 exactly
  const int x = blockIdx.x & 7;
  const int W = x * 125 + (blockIdx.x >> 3);
  const int g = W / 50;        // segment 0..19 (b*5 + kvq)
  const int qt = W % 50;
  const int b = g / KVSPLIT;
  const int kvq = g % KVSPLIT;
  const int qb0 = qt * 128;
  const int kv00 = kvq * KVRANGE;

  const u16* Qb = Qtm + ((size_t)b * NTOK + qb0 + w * 32 + l31) * CAv;
  const u16* Kb = Ktm + (size_t)b * NTOK * CAv;
  const u16* Vb = Vcm + (size_t)b * CAv * NTOK;

  sh8 qf[8];
#pragma unroll
  for (int kk = 0; kk < 8; kk++) qf[kk] = *(const sh8*)(Qb + kk * 16 + h * 8);

  // K DMA (4 inst/wave, 16 rows x 256B): inst i covers rows w*16 + 4i + (lane>>4),
  // key (4i + (lane>>4)) & 15 (w*16 mod 16 == 0; 4i + li <= 15, no wrap).
  // +64-row advance preserves keys. Per-instruction pointer (R10 rule).
  const int li = lane >> 4;
  const u16* ksrc[4];
#pragma unroll
  for (int i = 0; i < 4; i++) {
    const int kr = w * 16 + 4 * i + li;
    ksrc[i] = Kb + ((size_t)kv00 + kr) * CAv + (((lane & 15) ^ ((4 * i + li) & 15)) * 8);
  }
  // V DMA (4 inst/wave, 32 rows x 128B): c = w*32 + 8i + (lane>>3);
  // (c & 7) == (lane>>3) & 7 for all i -> one key, one pointer + offsets.
  const int vc = w * 32 + (lane >> 3);
  const u16* vsrc = Vb + (size_t)vc * NTOK + kv00 +
                    (((lane & 7) ^ ((lane >> 3) & 7)) * 8);

  // K-frag read offsets: row l31 (kv-half1 at +8192B, same key)
  int koff[8];
#pragma unroll
  for (int kk = 0; kk < 8; kk++)
    koff[kk] = l31 * 256 + (((2 * kk + h) ^ (l31 & 15)) << 4);
  // V-frag read offsets per 16-kv step b2 (rows = channels, 128B; (c&7)==l31&7)
  int voff[4];
#pragma unroll
  for (int b2 = 0; b2 < 4; b2++)
    voff[b2] = l31 * 128 + (((2 * b2 + h) ^ (l31 & 7)) << 4);

#define STAGE(p)                                                   \
  do {                                                             \
    u16* kb_ = (u16*)(smem + (p) * 32768) + w * 2048;              \
    gl_lds16(ksrc[0], kb_);                                        \
    gl_lds16(ksrc[1], kb_ + 512);                                  \
    gl_lds16(ksrc[2], kb_ + 1024);                                 \
    gl_lds16(ksrc[3], kb_ + 1536);                                 \
    u16* vb_ = (u16*)(smem + (p) * 32768 + 16384) + w * 2048;      \
    gl_lds16(vsrc, vb_);                                           \
    gl_lds16(vsrc + (size_t)8 * NTOK, vb_ + 512);                  \
    gl_lds16(vsrc + (size_t)16 * NTOK, vb_ + 1024);                \
    gl_lds16(vsrc + (size_t)24 * NTOK, vb_ + 1536);                \
    ksrc[0] += 64 * CAv; ksrc[1] += 64 * CAv;                      \
    ksrc[2] += 64 * CAv; ksrc[3] += 64 * CAv;                      \
    vsrc += 64;                                                    \
  } while (0)

  STAGE(0);
  asm volatile("s_waitcnt vmcnt(0)" ::: "memory");
  __builtin_amdgcn_s_barrier();

  f32x16 o[4];
#pragma unroll
  for (int i = 0; i < 4; i++) o[i] = zero16();
  float lsum = 0.f;

  int buf = 0;
  for (int t = 0; t < NTILES; t++) {
    if (t < NTILES - 1) STAGE(buf ^ 1);
    const unsigned char* kbuf = smem + buf * 32768;
    const unsigned char* vbuf = kbuf + 16384;
    __builtin_amdgcn_s_setprio(1);
    f32x16 s0 = zero16(), s1 = zero16();
#pragma unroll
    for (int kk = 0; kk < 8; kk++) {
      sh8 kfa = *(const sh8*)(kbuf + koff[kk]);
      sh8 kfb = *(const sh8*)(kbuf + 8192 + koff[kk]);
      s0 = __builtin_amdgcn_mfma_f32_32x32x16_bf16(kfa, qf[kk], s0, 0, 0, 0);
      s1 = __builtin_amdgcn_mfma_f32_32x32x16_bf16(kfb, qf[kk], s1, 0, 0, 0);
    }
    __builtin_amdgcn_s_setprio(0);
    // static-C softmax: P = exp2(S); pack via v_cvt_pk
    f32x16 p0, p1;
#pragma unroll
    for (int r = 0; r < 16; r++) {
      p0[r] = __builtin_exp2f(s0[r]);
      p1[r] = __builtin_exp2f(s1[r]);
    }
#pragma unroll
    for (int r = 0; r < 16; r++) lsum += p0[r] + p1[r];
    unsigned pkm0[4][2], pkm1[4][2];
#pragma unroll
    for (int rq = 0; rq < 4; rq++) {
      pkm0[rq][0] = pk2(p0[4 * rq + 0], p0[4 * rq + 1]);
      pkm0[rq][1] = pk2(p0[4 * rq + 2], p0[4 * rq + 3]);
      pkm1[rq][0] = pk2(p1[4 * rq + 0], p1[4 * rq + 1]);
      pkm1[rq][1] = pk2(p1[4 * rq + 2], p1[4 * rq + 3]);
    }
#pragma unroll
    for (int xx = 0; xx < 2; xx++) {
#pragma unroll
      for (int b2i = 0; b2i < 2; b2i++) {
        unsigned ow0, ow1, sd0, sd1;
        if (xx == 0) {
          ow0 = h ? pkm0[2 * b2i + 1][0] : pkm0[2 * b2i][0];
          ow1 = h ? pkm0[2 * b2i + 1][1] : pkm0[2 * b2i][1];
          sd0 = h ? pkm0[2 * b2i][0] : pkm0[2 * b2i + 1][0];
          sd1 = h ? pkm0[2 * b2i][1] : pkm0[2 * b2i + 1][1];
        } else {
          ow0 = h ? pkm1[2 * b2i + 1][0] : pkm1[2 * b2i][0];
          ow1 = h ? pkm1[2 * b2i + 1][1] : pkm1[2 * b2i][1];
          sd0 = h ? pkm1[2 * b2i][0] : pkm1[2 * b2i + 1][0];
          sd1 = h ? pkm1[2 * b2i][1] : pkm1[2 * b2i + 1][1];
        }
        unsigned rv0 = (unsigned)__shfl_xor((int)sd0, 32);
        unsigned rv1 = (unsigned)__shfl_xor((int)sd1, 32);
        uint4v fw = {h ? rv0 : ow0, h ? rv1 : ow1, h ? ow0 : rv0, h ? ow1 : rv1};
        sh8 pf = __builtin_bit_cast(sh8, fw);
        const int b2 = xx * 2 + b2i;
        __builtin_amdgcn_s_setprio(1);
#pragma unroll
        for (int ct = 0; ct < 4; ct++) {
          sh8 vf = *(const sh8*)(vbuf + ct * 4096 + voff[b2]);
          o[ct] = __builtin_amdgcn_mfma_f32_32x32x16_bf16(vf, pf, o[ct], 0, 0, 0);
        }
        __builtin_amdgcn_s_setprio(0);
      }
    }
    asm volatile("s_waitcnt vmcnt(0)" ::: "memory");
    __builtin_amdgcn_s_barrier();
    buf ^= 1;
  }
#undef STAGE

  lsum += __shfl_xor(lsum, 32);
  u16* op = Opart + (((size_t)kvq * BB + b) * NTOK + qb0 + w * 32 + l31) * CAv;
#pragma unroll
  for (int ct = 0; ct < 4; ct++)
#pragma unroll
    for (int rq = 0; rq < 4; rq++) {
      uint2v d = {pk2(o[ct][4 * rq + 0], o[ct][4 * rq + 1]),
                  pk2(o[ct][4 * rq + 2], o[ct][4 * rq + 3])};
      *(uint2v*)(op + ct * 32 + rq * 8 + h * 4) = d;
    }
  if (h == 0) {
    size_t mi = ((size_t)kvq * BB + b) * NTOK + qb0 + w * 32 + l31;
    Lpart[mi] = lsum;
  }
}

// ---------------- MFMA output projection + merge + residual (unchanged) ----------------
__global__ __launch_bounds__(512, 2) void outproj(const float* __restrict__ met,
                                                  const u16* __restrict__ woB,
                                                  const float* __restrict__ bo,
                                                  const u16* __restrict__ Opart,
                                                  const float* __restrict__ Lpart,
                                                  float* __restrict__ out) {
  const int tid = threadIdx.x;
  const int w = tid >> 6;
  const int lane = tid & 63;
  const int l31 = lane & 31;
  const int h = lane >> 5;

  const int b = blockIdx.x / 100;
  const int tokb = (blockIdx.x % 100) * 64;
  const int chg = (w & 3) * 64;
  const int ct = w >> 2;
  const int tok = tokb + ct * 32 + l31;
  const size_t n = (size_t)b * NTOK + tok;
  const size_t PSTR = (size_t)BB * NTOK;

  const u16* wb0 = woB + (size_t)(chg + l31) * 128 + h * 8;
  const u16* wb1 = woB + (size_t)(chg + 32 + l31) * 128 + h * 8;
  sh8 a0[8], a1[8];
#pragma unroll
  for (int kk = 0; kk < 8; kk++) {
    a0[kk] = *(const sh8*)(wb0 + kk * 16);
    a1[kk] = *(const sh8*)(wb1 + kk * 16);
  }

  float L = 0.f;
#pragma unroll
  for (int i = 0; i < KVSPLIT; i++) L += Lpart[i * PSTR + n];
  const float rL = 1.f / L;

  f32x16 acc0 = zero16(), acc1 = zero16();
#pragma unroll
  for (int kk = 0; kk < 8; kk++) {
    float s[8];
#pragma unroll
    for (int j = 0; j < 8; j++) s[j] = 0.f;
#pragma unroll
    for (int i = 0; i < KVSPLIT; i++) {
      sh8 v = *(const sh8*)(Opart + (i * PSTR + n) * CAv + kk * 16 + 8 * h);
#pragma unroll
      for (int j = 0; j < 8; j++) s[j] += bf2f((u16)v[j]);
    }
    uint4v u = {pk2(s[0] * rL, s[1] * rL), pk2(s[2] * rL, s[3] * rL),
                pk2(s[4] * rL, s[5] * rL), pk2(s[6] * rL, s[7] * rL)};
    sh8 bf = __builtin_bit_cast(sh8, u);
    acc0 = __builtin_amdgcn_mfma_f32_32x32x16_bf16(a0[kk], bf, acc0, 0, 0, 0);
    acc1 = __builtin_amdgcn_mfma_f32_32x32x16_bf16(a1[kk], bf, acc1, 0, 0, 0);
  }
#pragma unroll
  for (int r = 0; r < 16; r++) {
    const int ro = (r & 3) + 8 * (r >> 2) + 4 * h;
    const int ch0 = chg + ro;
    const int ch1 = chg + 32 + ro;
    size_t i0 = ((size_t)b * CMv + ch0) * NTOK + tok;
    size_t i1 = ((size_t)b * CMv + ch1) * NTOK + tok;
    out[i0] = met[i0] + acc0[r] + bo[ch0];
    out[i1] = met[i1] + acc1[r] + bo[ch1];
  }
}

extern "C" void kernel_launch(void* const* d_in, const int* in_sizes, int n_in,
                              void* d_out, int out_size, void* d_ws, size_t ws_size,
                              hipStream_t stream) {
  const float* met = (const float*)d_in[0];
  const float* ter = (const float*)d_in[1];
  const float* wq = (const float*)d_in[2];
  const float* bq = (const float*)d_in[3];
  const float* wk = (const float*)d_in[4];
  const float* bk = (const float*)d_in[5];
  const float* wv = (const float*)d_in[6];
  const float* bv = (const float*)d_in[7];
  const float* wo = (const float*)d_in[8];
  const float* bo = (const float*)d_in[9];
  float* out = (float*)d_out;

  u16* Qtm = (u16*)d_ws;
  u16* Ktm = Qtm + (size_t)BB * NTOK * CAv;
  u16* Vcm = Ktm + (size_t)BB * NTOK * CAv;
  u16* Opart = Vcm + (size_t)BB * NTOK * CAv;
  float* Lpart = (float*)(Opart + (size_t)KVSPLIT * BB * NTOK * CAv);
  u16* wqB = (u16*)(Lpart + (size_t)KVSPLIT * BB * NTOK);
  u16* wkB = wqB + 128 * 256;
  u16* wvB = wkB + 128 * 64;
  u16* woB = wvB + 128 * 64;
  float* bqs = (float*)(woB + 256 * 128);

  prep<<<dim3(40), dim3(256), 0, stream>>>(wq, bq, wk, wv, wo, wqB, bqs, wkB, wvB, woB);
  qkvproj<<<dim3(400), dim3(512), 0, stream>>>(met, ter, wqB, bqs, wkB, bk,
                                               wvB, bv, Qtm, Ktm, Vcm);
  attn<<<dim3(1000), dim3(256), 0, stream>>>(Qtm, Ktm, Vcm, Opart, Lpart);
  outproj<<<dim3(400), dim3(512), 0, stream>>>(met, woB, bo, Opart, Lpart, out);
}